// Round 1
// baseline (748.750 us; speedup 1.0000x reference)
//
#include <hip/hip_runtime.h>
#include <math.h>

#define Bdim 64
#define Sdim 2048
#define Hdim 1024

// Kernel A: v[b,h] = sum_k hid[b,k] * W[k,h]   (v = h @ W, torch Linear with W (out,in))
//           c[b]   = sum_k hid[b,k] * bias[k]
// grid (5, B): bx 0..3 compute 256 h-columns each; bx==4 computes c[b].
__global__ __launch_bounds__(256)
void proj_v_kernel(const float* __restrict__ hid, const float* __restrict__ W,
                   const float* __restrict__ bias, float* __restrict__ v,
                   float* __restrict__ c)
{
    __shared__ float sh[Hdim];
    __shared__ float red[4];
    const int b   = blockIdx.y;
    const int tid = threadIdx.x;

    for (int i = tid; i < Hdim; i += 256) sh[i] = hid[b * Hdim + i];
    __syncthreads();

    if (blockIdx.x == 4) {
        float acc = 0.f;
        for (int k = tid; k < Hdim; k += 256) acc += sh[k] * bias[k];
        for (int off = 32; off > 0; off >>= 1) acc += __shfl_down(acc, off, 64);
        if ((tid & 63) == 0) red[tid >> 6] = acc;
        __syncthreads();
        if (tid == 0) c[b] = red[0] + red[1] + red[2] + red[3];
        return;
    }

    const int h = blockIdx.x * 256 + tid;
    const float* Wp = W + h;            // column h, stride Hdim
    float acc = 0.f;
    #pragma unroll 8
    for (int k = 0; k < Hdim; ++k)
        acc = fmaf(sh[k], Wp[(size_t)k * Hdim], acc);
    v[b * Hdim + h] = acc;
}

// Kernel B: energies[b,s] = enc[b,s,:] . v[b,:] + c[b], written into d_out.
// One wave per s; lane loads 4x float4 per s (fully coalesced, 1 KiB per wave
// per load instr); v fragment preloaded per-lane into 4 float4 registers.
// grid (S/32, B), block 256 (4 waves x 8 s each).
__global__ __launch_bounds__(256)
void energy_kernel(const float* __restrict__ enc, const float* __restrict__ v,
                   const float* __restrict__ c, float* __restrict__ out)
{
    const int b      = blockIdx.y;
    const int lane   = threadIdx.x & 63;
    const int wave   = threadIdx.x >> 6;
    const int s_base = blockIdx.x * 32 + wave * 8;

    const float4* vrow = (const float4*)(v + b * Hdim);
    const float4 v0 = vrow[lane];
    const float4 v1 = vrow[lane + 64];
    const float4 v2 = vrow[lane + 128];
    const float4 v3 = vrow[lane + 192];
    const float  cb = c[b];

    const float4* erow = (const float4*)(enc + ((size_t)b * Sdim + s_base) * Hdim);

    #pragma unroll 2
    for (int i = 0; i < 8; ++i) {
        const float4* ep = erow + (size_t)i * (Hdim / 4);
        const float4 a0 = ep[lane];
        const float4 a1 = ep[lane + 64];
        const float4 a2 = ep[lane + 128];
        const float4 a3 = ep[lane + 192];

        float acc = a0.x * v0.x + a0.y * v0.y + a0.z * v0.z + a0.w * v0.w;
        acc      += a1.x * v1.x + a1.y * v1.y + a1.z * v1.z + a1.w * v1.w;
        acc      += a2.x * v2.x + a2.y * v2.y + a2.z * v2.z + a2.w * v2.w;
        acc      += a3.x * v3.x + a3.y * v3.y + a3.z * v3.z + a3.w * v3.w;

        #pragma unroll
        for (int off = 1; off < 64; off <<= 1)
            acc += __shfl_xor(acc, off, 64);

        if (lane == 0) out[b * Sdim + s_base + i] = acc + cb;
    }
}

// Kernel C: in-place softmax over the batch axis (column s of the B x S
// energies matrix). One thread per s; 64 values held in registers.
// grid S/64, block 64.
__global__ __launch_bounds__(64)
void softmax_kernel(float* __restrict__ out)
{
    const int s = blockIdx.x * 64 + threadIdx.x;
    float vals[Bdim];
    #pragma unroll
    for (int b = 0; b < Bdim; ++b) vals[b] = out[b * Sdim + s];
    float m = vals[0];
    #pragma unroll
    for (int b = 1; b < Bdim; ++b) m = fmaxf(m, vals[b]);
    float sum = 0.f;
    #pragma unroll
    for (int b = 0; b < Bdim; ++b) { vals[b] = __expf(vals[b] - m); sum += vals[b]; }
    const float inv = 1.f / sum;
    #pragma unroll
    for (int b = 0; b < Bdim; ++b) out[b * Sdim + s] = vals[b] * inv;
}

extern "C" void kernel_launch(void* const* d_in, const int* in_sizes, int n_in,
                              void* d_out, int out_size, void* d_ws, size_t ws_size,
                              hipStream_t stream)
{
    const float* hid  = (const float*)d_in[0];   // (1, B, H)
    const float* enc  = (const float*)d_in[1];   // (B, S, H)
    const float* W    = (const float*)d_in[2];   // (H, H)  [out, in]
    const float* bias = (const float*)d_in[3];   // (H,)
    float* out = (float*)d_out;                  // (B, S)

    float* v = (float*)d_ws;                     // B*H floats = 256 KiB
    float* c = v + Bdim * Hdim;                  // B floats

    proj_v_kernel<<<dim3(5, Bdim), 256, 0, stream>>>(hid, W, bias, v, c);
    energy_kernel<<<dim3(Sdim / 32, Bdim), 256, 0, stream>>>(enc, v, c, out);
    softmax_kernel<<<dim3(Sdim / 64), 64, 0, stream>>>(out);
}

// Round 3
// 681.960 us; speedup vs baseline: 1.0979x; 1.0979x over previous
//
#include <hip/hip_runtime.h>
#include <math.h>

#define Bdim 64
#define Sdim 2048
#define Hdim 1024

typedef float f4 __attribute__((ext_vector_type(4)));   // clang vector: valid for nontemporal builtins

// Kernel A: v[b,j] = sum_k hid[b,k] * W[k,j]; c[b] = sum_k hid[b,k] * bias[k].
// grid (4, B), block 256. Each block covers 256 j-columns (64 float4 groups),
// k-range split across the 4 waves (chain length 256 -> LDS-reduced).
// W f4 loads: 64 lanes x 16 B = 1 KiB contiguous per instruction.
__global__ __launch_bounds__(256)
void proj_v_kernel(const float* __restrict__ hid, const float* __restrict__ W,
                   const float* __restrict__ bias, float* __restrict__ v,
                   float* __restrict__ c)
{
    __shared__ float sh[Hdim];
    __shared__ f4    red[4][64];
    __shared__ float cr[4];

    const int b    = blockIdx.y;
    const int t    = threadIdx.x;
    const int w    = t >> 6;
    const int lane = t & 63;

    for (int i = t; i < Hdim; i += 256) sh[i] = hid[b * Hdim + i];
    __syncthreads();

    const f4* W4 = (const f4*)W;                  // W4[k*256 + j4]
    const int j4 = blockIdx.x * 64 + lane;        // float4 column group

    f4 a0 = {0.f, 0.f, 0.f, 0.f};
    f4 a1 = {0.f, 0.f, 0.f, 0.f};
    const int k0 = w * 256;
    #pragma unroll 4
    for (int k = k0; k < k0 + 256; k += 2) {
        const f4 w0 = W4[(size_t)k * 256 + j4];
        const f4 w1 = W4[(size_t)(k + 1) * 256 + j4];
        a0 += sh[k] * w0;
        a1 += sh[k + 1] * w1;
    }
    a0 += a1;
    red[w][lane] = a0;
    __syncthreads();

    if (w == 0) {
        const f4 r = red[0][lane] + red[1][lane] + red[2][lane] + red[3][lane];
        ((f4*)v)[b * 256 + j4] = r;
    }

    if (blockIdx.x == 0) {                        // c[b] once per batch row
        float pc = 0.f;
        for (int k = t; k < Hdim; k += 256) pc = fmaf(sh[k], bias[k], pc);
        for (int off = 32; off > 0; off >>= 1) pc += __shfl_down(pc, off, 64);
        if (lane == 0) cr[w] = pc;
        __syncthreads();
        if (t == 0) c[b] = cr[0] + cr[1] + cr[2] + cr[3];
    }
}

// Kernel B: energies[b,s] = enc[b,s,:] . v[b,:] + c[b]  -> staged in d_out.
// One wave per s-row dot; nontemporal f4 loads (enc has zero reuse).
// grid (S/32, B), block 256 (4 waves x 8 s each).
__global__ __launch_bounds__(256)
void energy_kernel(const float* __restrict__ enc, const float* __restrict__ v,
                   const float* __restrict__ c, float* __restrict__ out)
{
    const int b      = blockIdx.y;
    const int lane   = threadIdx.x & 63;
    const int wave   = threadIdx.x >> 6;
    const int s_base = blockIdx.x * 32 + wave * 8;

    const f4* vrow = (const f4*)(v + b * Hdim);
    const f4 v0 = vrow[lane];
    const f4 v1 = vrow[lane + 64];
    const f4 v2 = vrow[lane + 128];
    const f4 v3 = vrow[lane + 192];
    const float cb = c[b];

    const f4* erow = (const f4*)(enc + ((size_t)b * Sdim + s_base) * Hdim);

    #pragma unroll 2
    for (int i = 0; i < 8; ++i) {
        const f4* ep = erow + (size_t)i * (Hdim / 4);
        const f4 a0 = __builtin_nontemporal_load(ep + lane);
        const f4 a1 = __builtin_nontemporal_load(ep + lane + 64);
        const f4 a2 = __builtin_nontemporal_load(ep + lane + 128);
        const f4 a3 = __builtin_nontemporal_load(ep + lane + 192);

        float acc = a0.x * v0.x + a0.y * v0.y + a0.z * v0.z + a0.w * v0.w;
        acc      += a1.x * v1.x + a1.y * v1.y + a1.z * v1.z + a1.w * v1.w;
        acc      += a2.x * v2.x + a2.y * v2.y + a2.z * v2.z + a2.w * v2.w;
        acc      += a3.x * v3.x + a3.y * v3.y + a3.z * v3.z + a3.w * v3.w;

        #pragma unroll
        for (int off = 1; off < 64; off <<= 1)
            acc += __shfl_xor(acc, off, 64);

        if (lane == 0) out[b * Sdim + s_base + i] = acc + cb;
    }
}

// Kernel C: softmax over batch axis, in place on d_out (B x S).
// grid 32, block 256: block covers 64 s-columns; wave w holds b in [16w,16w+16).
// All loads/stores coalesced (lane = s); cross-wave max/sum via LDS.
__global__ __launch_bounds__(256)
void softmax_kernel(float* __restrict__ out)
{
    __shared__ float smax[4][64];
    __shared__ float ssum[4][64];
    const int t    = threadIdx.x;
    const int w    = t >> 6;
    const int lane = t & 63;
    const int s    = blockIdx.x * 64 + lane;

    float vals[16];
    float m = -1e30f;
    #pragma unroll
    for (int i = 0; i < 16; ++i) {
        vals[i] = out[(size_t)(w * 16 + i) * Sdim + s];
        m = fmaxf(m, vals[i]);
    }
    smax[w][lane] = m;
    __syncthreads();
    m = fmaxf(fmaxf(smax[0][lane], smax[1][lane]),
              fmaxf(smax[2][lane], smax[3][lane]));

    float sum = 0.f;
    #pragma unroll
    for (int i = 0; i < 16; ++i) { vals[i] = __expf(vals[i] - m); sum += vals[i]; }
    ssum[w][lane] = sum;
    __syncthreads();
    const float inv = 1.f / (ssum[0][lane] + ssum[1][lane] +
                             ssum[2][lane] + ssum[3][lane]);
    #pragma unroll
    for (int i = 0; i < 16; ++i)
        out[(size_t)(w * 16 + i) * Sdim + s] = vals[i] * inv;
}

extern "C" void kernel_launch(void* const* d_in, const int* in_sizes, int n_in,
                              void* d_out, int out_size, void* d_ws, size_t ws_size,
                              hipStream_t stream)
{
    const float* hid  = (const float*)d_in[0];   // (1, B, H)
    const float* enc  = (const float*)d_in[1];   // (B, S, H)
    const float* W    = (const float*)d_in[2];   // (H, H)  [out, in]
    const float* bias = (const float*)d_in[3];   // (H,)
    float* out = (float*)d_out;                  // (B, S)

    float* v = (float*)d_ws;                     // B*H floats = 256 KiB
    float* c = v + Bdim * Hdim;                  // B floats

    proj_v_kernel<<<dim3(4, Bdim), 256, 0, stream>>>(hid, W, bias, v, c);
    energy_kernel<<<dim3(Sdim / 32, Bdim), 256, 0, stream>>>(enc, v, c, out);
    softmax_kernel<<<dim3(Sdim / 64), 256, 0, stream>>>(out);
}